// Round 9
// baseline (3525.174 us; speedup 1.0000x reference)
//
#include <hip/hip_runtime.h>
#include <math.h>

#define SEQ  4096
#define NG   8          // batch groups (16 rows each)
#define GB   16
#define RING 2          // handoff ring slots per group
#define TILE 32         // timesteps per tile

typedef _Float16 f16x8 __attribute__((ext_vector_type(8)));
typedef _Float16 f16x4 __attribute__((ext_vector_type(4)));
typedef float    f32x4 __attribute__((ext_vector_type(4)));

__device__ __forceinline__ float rcp_(float x){ return __builtin_amdgcn_rcpf(x); }
__device__ __forceinline__ float sigm(float v){ return rcp_(1.0f + __expf(-v)); }
__device__ __forceinline__ float tanh_(float v){
    float av = fabsf(v);
    float e  = __expf(-2.0f * av);
    float r  = (1.0f - e) * rcp_(1.0f + e);
    return copysignf(r, v);
}
__device__ __forceinline__ float comp(const float4& v, int i){
    return i == 0 ? v.x : i == 1 ? v.y : i == 2 ? v.z : v.w;   // folds for literal i
}

__global__ void zero_flags(int* f, int n) {
    int i = blockIdx.x * blockDim.x + threadIdx.x;
    if (i < n) f[i] = 0;
}

// 16 blocks: block 2g = layer0 of batch group g (producer), 2g+1 = layer1
// (consumer). 256 threads = 4 waves. Per step: gates[16b x 256g] =
// op[16b x 128k] @ W^T via 16 MFMA 16x16x32_f16 per wave.
// Wave q owns M-tiles {q, q+4, q+8, q+12} -> lane holds i,f,g,o of units
// u0..u0+3 (u0 = 16q+4*(l>>4)) for batch (l&15): update is lane-local.
// Weights live as 16 f16x8 MFMA A-fragments per lane (load->cvt->pack chain:
// not rematerializable, so they finally stay register-resident).
__global__ __launch_bounds__(256, 1) void lstm2_mfma(
    const float* __restrict__ x,
    const float* __restrict__ wih0, const float* __restrict__ whh0,
    const float* __restrict__ b0,
    const float* __restrict__ wih1, const float* __restrict__ whh1,
    const float* __restrict__ b1,
    float* __restrict__ out,
    _Float16* __restrict__ ring,   // [NG][RING][TILE][1024] f16
    int* __restrict__ rdy,         // [NG][128]
    int* __restrict__ cons)        // [NG][128]
{
    const int bid  = blockIdx.x;
    const int g    = bid >> 1;
    const int role = bid & 1;          // 0 producer (layer0), 1 consumer (layer1)
    const int tid  = threadIdx.x;
    const int q    = tid >> 6;         // wave
    const int l    = tid & 63;
    const int nl   = l & 15;           // batch column
    const int lg   = l >> 4;

    // optile[tau]: B-frags for k=0..63 (x for L0, h0 for L1): [kt2][lg4][n16][j8]
    __shared__ __align__(16) _Float16 optile[TILE][1024];
    // hbuf: B-frags for k=64..127 (own recurrent h), double-buffered
    __shared__ __align__(16) _Float16 hbuf[2][1024];
    // consumer h1 staging for coalesced output flush (16 steps)
    __shared__ float otile[64][GB][17];

    const float* Wih = role ? wih1 : wih0;
    const float* Whh = role ? whh1 : whh0;
    const float* Bs  = role ? b1   : b0;

    // ---- weight A-fragments: wf[s][kt], gate row = 64s + 16q + (l&15) ----
    f16x8 wf[4][4];
#pragma unroll
    for (int s = 0; s < 4; ++s) {
        const int gate = 64 * s + 16 * q + nl;
#pragma unroll
        for (int kt = 0; kt < 4; ++kt) {
            const int k8 = kt * 32 + lg * 8;
            const float* src = (k8 < 64) ? (Wih + (size_t)gate * 64 + k8)
                                         : (Whh + (size_t)gate * 64 + (k8 - 64));
            float4 lo = *(const float4*)(src);
            float4 hi = *(const float4*)(src + 4);
            f16x8 f;
            f[0]=(_Float16)lo.x; f[1]=(_Float16)lo.y; f[2]=(_Float16)lo.z; f[3]=(_Float16)lo.w;
            f[4]=(_Float16)hi.x; f[5]=(_Float16)hi.y; f[6]=(_Float16)hi.z; f[7]=(_Float16)hi.w;
            wf[s][kt] = f;
        }
    }

    // ---- bias as MFMA C-init: bias4[s][r] = Bs[64s + u0 + r] ----
    const int u0 = 16 * q + 4 * lg;
    f32x4 bias4[4];
#pragma unroll
    for (int s = 0; s < 4; ++s) {
        float4 bv = *(const float4*)(Bs + 64 * s + u0);
        f32x4 t; t[0]=bv.x; t[1]=bv.y; t[2]=bv.z; t[3]=bv.w;
        bias4[s] = t;
    }

    for (int i = tid; i < 1024; i += 256) {
        hbuf[0][i] = (_Float16)0.f; hbuf[1][i] = (_Float16)0.f;
    }

    const float* xb = x + (size_t)(g * GB) * 64 * SEQ;
    _Float16* ringg = ring + (size_t)g * RING * TILE * 1024;

    // h-write indices (same formula serves hbuf k=64+u and ring k'=u)
    const int ktl = u0 >> 5;            // 0 or 1
    const int lg2 = (u0 >> 3) & 3;
    const int j0  = u0 & 7;             // 0 or 4
    const int hoff = (ktl * 4 + lg2) * 128 + nl * 8 + j0;

    float c0 = 0.f, c1 = 0.f, c2 = 0.f, c3 = 0.f;

    for (int n = 0; n < SEQ; ++n) {
        const int tau = n & (TILE - 1);
        if (tau == 0) {
            const int T = n >> 5;
            if (role == 0) {
                if (T >= RING && tid == 0) {
                    while (__hip_atomic_load(&cons[g * 128 + T - RING],
                                             __ATOMIC_ACQUIRE, __HIP_MEMORY_SCOPE_AGENT) == 0)
                        __builtin_amdgcn_s_sleep(8);
                }
                __syncthreads();
                // stage x tile T -> optile frag layout. thread=(n16,kt2,lg4,ch2)
                {
                    const int sn  = tid & 15;
                    const int skt = (tid >> 4) & 1;
                    const int slg = (tid >> 5) & 3;
                    const int sch = (tid >> 7) & 1;
                    const int cb  = skt * 32 + slg * 8 + sch * 4;
                    const float* rb = xb + ((size_t)sn * 64 + cb) * SEQ + n;
                    float4 rowv[4][8];
#pragma unroll
                    for (int cc = 0; cc < 4; ++cc) {
                        const float* rp = rb + (size_t)cc * SEQ;
#pragma unroll
                        for (int w8 = 0; w8 < 8; ++w8)
                            rowv[cc][w8] = *(const float4*)(rp + 4 * w8);
                    }
                    const int dst0 = (skt * 4 + slg) * 128 + sn * 8 + sch * 4;
#pragma unroll
                    for (int t = 0; t < TILE; ++t) {
                        f16x4 pk;
                        pk[0] = (_Float16)comp(rowv[0][t >> 2], t & 3);
                        pk[1] = (_Float16)comp(rowv[1][t >> 2], t & 3);
                        pk[2] = (_Float16)comp(rowv[2][t >> 2], t & 3);
                        pk[3] = (_Float16)comp(rowv[3][t >> 2], t & 3);
                        *(f16x4*)&optile[t][dst0] = pk;
                    }
                }
                __syncthreads();
            } else {
                if (tid == 0) {
                    while (__hip_atomic_load(&rdy[g * 128 + T],
                                             __ATOMIC_ACQUIRE, __HIP_MEMORY_SCOPE_AGENT) == 0)
                        __builtin_amdgcn_s_sleep(8);
                }
                __syncthreads();
                const f16x8* src = (const f16x8*)(ringg + (size_t)(T % RING) * TILE * 1024);
                f16x8* dst = (f16x8*)&optile[0][0];
                for (int i = tid; i < TILE * 1024 / 8; i += 256) dst[i] = src[i];
                __syncthreads();
                if (tid == 0)
                    __hip_atomic_store(&cons[g * 128 + T], 1,
                                       __ATOMIC_RELEASE, __HIP_MEMORY_SCOPE_AGENT);
            }
        }

        // ---- B-fragments ----
        const _Float16* opt = optile[tau];
        const _Float16* hb  = hbuf[n & 1];
        f16x8 bf[4];
        bf[0] = *(const f16x8*)(opt + (0 * 4 + lg) * 128 + nl * 8);
        bf[1] = *(const f16x8*)(opt + (1 * 4 + lg) * 128 + nl * 8);
        bf[2] = *(const f16x8*)(hb  + (0 * 4 + lg) * 128 + nl * 8);
        bf[3] = *(const f16x8*)(hb  + (1 * 4 + lg) * 128 + nl * 8);

        // ---- 16 MFMA: acc[s] = sum_kt W[s][kt] * op[kt] + bias ----
        f32x4 a0 = bias4[0], a1 = bias4[1], a2 = bias4[2], a3 = bias4[3];
#pragma unroll
        for (int kt = 0; kt < 4; ++kt) {
            a0 = __builtin_amdgcn_mfma_f32_16x16x32_f16(wf[0][kt], bf[kt], a0, 0, 0, 0);
            a1 = __builtin_amdgcn_mfma_f32_16x16x32_f16(wf[1][kt], bf[kt], a1, 0, 0, 0);
            a2 = __builtin_amdgcn_mfma_f32_16x16x32_f16(wf[2][kt], bf[kt], a2, 0, 0, 0);
            a3 = __builtin_amdgcn_mfma_f32_16x16x32_f16(wf[3][kt], bf[kt], a3, 0, 0, 0);
        }

        // ---- lane-local update: 4 cells (units u0..u0+3, batch nl) ----
        float h0v, h1v, h2v, h3v;
        {
            float iv = sigm(a0[0]), fv = sigm(a1[0]), gv = tanh_(a2[0]), ov = sigm(a3[0]);
            c0 = fv * c0 + iv * gv; h0v = ov * tanh_(c0);
        }
        {
            float iv = sigm(a0[1]), fv = sigm(a1[1]), gv = tanh_(a2[1]), ov = sigm(a3[1]);
            c1 = fv * c1 + iv * gv; h1v = ov * tanh_(c1);
        }
        {
            float iv = sigm(a0[2]), fv = sigm(a1[2]), gv = tanh_(a2[2]), ov = sigm(a3[2]);
            c2 = fv * c2 + iv * gv; h2v = ov * tanh_(c2);
        }
        {
            float iv = sigm(a0[3]), fv = sigm(a1[3]), gv = tanh_(a2[3]), ov = sigm(a3[3]);
            c3 = fv * c3 + iv * gv; h3v = ov * tanh_(c3);
        }

        f16x4 hp;
        hp[0] = (_Float16)h0v; hp[1] = (_Float16)h1v;
        hp[2] = (_Float16)h2v; hp[3] = (_Float16)h3v;
        *(f16x4*)(hbuf[(n + 1) & 1] + hoff) = hp;

        if (role == 0) {
            *(f16x4*)(ringg + (size_t)((n >> 5) % RING) * TILE * 1024
                      + (size_t)tau * 1024 + hoff) = hp;
        } else {
            const int t15 = tau & 15;
            otile[u0 + 0][nl][t15] = h0v;
            otile[u0 + 1][nl][t15] = h1v;
            otile[u0 + 2][nl][t15] = h2v;
            otile[u0 + 3][nl][t15] = h3v;
        }

        __syncthreads();

        if (role == 0) {
            if (tau == TILE - 1 && tid == 0) {
                __threadfence();
                __hip_atomic_store(&rdy[g * 128 + (n >> 5)], 1,
                                   __ATOMIC_RELEASE, __HIP_MEMORY_SCOPE_AGENT);
            }
        } else if ((tau & 15) == 15) {
            const int t0 = n - 15;
#pragma unroll
            for (int rr = 0; rr < 4; ++rr) {
                const int row = tid * 4 + rr;    // row = u*16 + nb
                const int uu = row >> 4, nb = row & 15;
                float* op_ = out + ((size_t)(g * GB + nb) * 64 + uu) * SEQ + t0;
                const float* sr = &otile[uu][nb][0];
                float4 v0 = make_float4(sr[0],  sr[1],  sr[2],  sr[3]);
                float4 v1 = make_float4(sr[4],  sr[5],  sr[6],  sr[7]);
                float4 v2 = make_float4(sr[8],  sr[9],  sr[10], sr[11]);
                float4 v3 = make_float4(sr[12], sr[13], sr[14], sr[15]);
                *(float4*)(op_ + 0)  = v0;
                *(float4*)(op_ + 4)  = v1;
                *(float4*)(op_ + 8)  = v2;
                *(float4*)(op_ + 12) = v3;
            }
            __syncthreads();
        }
    }
}

extern "C" void kernel_launch(void* const* d_in, const int* in_sizes, int n_in,
                              void* d_out, int out_size, void* d_ws, size_t ws_size,
                              hipStream_t stream) {
    const float* x    = (const float*)d_in[0];
    const float* wih0 = (const float*)d_in[1];
    const float* whh0 = (const float*)d_in[2];
    const float* b0   = (const float*)d_in[3];
    const float* wih1 = (const float*)d_in[4];
    const float* whh1 = (const float*)d_in[5];
    const float* b1   = (const float*)d_in[6];
    float* out = (float*)d_out;

    int* rdy  = (int*)d_ws;                              // [NG][128]
    int* cons = rdy + NG * 128;                          // [NG][128]
    _Float16* ring = (_Float16*)((char*)d_ws + 8192);    // [NG][RING][TILE][1024]

    zero_flags<<<8, 256, 0, stream>>>(rdy, NG * 128 * 2);
    lstm2_mfma<<<2 * NG, 256, 0, stream>>>(x, wih0, whh0, b0, wih1, whh1, b1,
                                           out, ring, rdy, cons);
}